// Round 4
// baseline (158114.771 us; speedup 1.0000x reference)
//
#include <hip/hip_runtime.h>

#define Bq 32
#define Sq 2048
#define Iq 128
#define Hq 512
#define Oq 128
#define NWG 256
#define NT 256
#define KB 256
#define SS 260  // LDS row stride (floats): 16B-aligned, breaks pow2

__device__ __forceinline__ float sigmoidf_(float v) {
    return 1.0f / (1.0f + __expf(-v));
}

// Relaxed agent-scope (LLC-coherent) access — no cache-maintenance fences.
__device__ __forceinline__ float ld_coh(const float* p) {
    return __hip_atomic_load(p, __ATOMIC_RELAXED, __HIP_MEMORY_SCOPE_AGENT);
}
__device__ __forceinline__ void st_coh(float* p, float v) {
    __hip_atomic_store(p, v, __ATOMIC_RELAXED, __HIP_MEMORY_SCOPE_AGENT);
}
__device__ __forceinline__ int ld_cohi(const int* p) {
    return __hip_atomic_load(p, __ATOMIC_RELAXED, __HIP_MEMORY_SCOPE_AGENT);
}
__device__ __forceinline__ void st_cohi(int* p, int v) {
    __hip_atomic_store(p, v, __ATOMIC_RELAXED, __HIP_MEMORY_SCOPE_AGENT);
}

// Store/scan grid barrier: NO atomic RMWs (RMW serialization was ~13us/round).
// Arrival: block stores gen to its own flag dword (256 flags = 16 lines,
// parallel channels). Master (block 0, wave 0) scans flags with 4 coherent
// loads/lane, publishes go. Generations monotone -> no resets, no ABA.
__device__ __forceinline__ void gridbar(int* bar, int gen) {
    asm volatile("s_waitcnt vmcnt(0) lgkmcnt(0)" ::: "memory");
    __syncthreads();
    int* go = bar + 320;  // own cache line
    if (blockIdx.x == 0) {
        if (threadIdx.x < 64) {
            int idx = threadIdx.x << 2;
            for (;;) {
                int f0 = (idx == 0) ? gen : ld_cohi(bar + idx);
                int f1 = ld_cohi(bar + idx + 1);
                int f2 = ld_cohi(bar + idx + 2);
                int f3 = ld_cohi(bar + idx + 3);
                bool ok = (f0 >= gen) & (f1 >= gen) & (f2 >= gen) & (f3 >= gen);
                if (__all(ok)) break;
                __builtin_amdgcn_s_sleep(2);
            }
        }
        __syncthreads();
        if (threadIdx.x == 0) {
            asm volatile("s_waitcnt vmcnt(0)" ::: "memory");
            st_cohi(go, gen);
        }
    } else {
        if (threadIdx.x == 0) {
            st_cohi(bar + blockIdx.x, gen);
            while (ld_cohi(go) < gen) __builtin_amdgcn_s_sleep(2);
        }
        __syncthreads();
    }
}

// Stage 32 x 256 chunk of mutable state (coherent loads) into sst[b][k].
__device__ __forceinline__ void stage256(float* sst, const float* g,
                                         long rowStride, int k0) {
    __syncthreads();
    float4 v[8];
#pragma unroll
    for (int u = 0; u < 8; ++u) {
        int i = threadIdx.x + u * NT;
        int b = i & 31, k4 = i >> 5;
        const float* p = g + (long)b * rowStride + k0 + (k4 << 2);
        v[u].x = ld_coh(p);
        v[u].y = ld_coh(p + 1);
        v[u].z = ld_coh(p + 2);
        v[u].w = ld_coh(p + 3);
    }
#pragma unroll
    for (int u = 0; u < 8; ++u) {
        int i = threadIdx.x + u * NT;
        int b = i & 31, k4 = i >> 5;
        *(float4*)(sst + b * SS + (k4 << 2)) = v[u];
    }
    __syncthreads();
}

// Stage 32 x 128 chunk of immutable x (plain cached loads).
__device__ __forceinline__ void stage128p(float* sst, const float* g,
                                          long rowStride) {
    __syncthreads();
#pragma unroll
    for (int u = 0; u < 4; ++u) {
        int i = threadIdx.x + u * NT;
        int b = i & 31, k4 = i >> 5;
        float4 v = *(const float4*)(g + (long)b * rowStride + (k4 << 2));
        *(float4*)(sst + b * SS + (k4 << 2)) = v;
    }
    __syncthreads();
}

// Two weight rows vs one staged column b (OPT=2: LDS column amortized).
__device__ __forceinline__ float2 dotC2(const float* sst,
                                        const float* __restrict__ W0,
                                        const float* __restrict__ W1, int b,
                                        int K) {
    const float* s = sst + b * SS;
    float a0 = 0.f, a1 = 0.f, a2 = 0.f, a3 = 0.f;
    float c0 = 0.f, c1 = 0.f, c2 = 0.f, c3 = 0.f;
#pragma unroll 8
    for (int k = 0; k < K; k += 4) {
        float4 h = *(const float4*)(s + k);
        float4 w = *(const float4*)(W0 + k);
        float4 u = *(const float4*)(W1 + k);
        a0 = fmaf(w.x, h.x, a0);
        a1 = fmaf(w.y, h.y, a1);
        a2 = fmaf(w.z, h.z, a2);
        a3 = fmaf(w.w, h.w, a3);
        c0 = fmaf(u.x, h.x, c0);
        c1 = fmaf(u.y, h.y, c1);
        c2 = fmaf(u.z, h.z, c2);
        c3 = fmaf(u.w, h.w, c3);
    }
    return make_float2((a0 + a1) + (a2 + a3), (c0 + c1) + (c2 + c3));
}

__device__ __forceinline__ float dotC1(const float* sst,
                                       const float* __restrict__ W0, int b,
                                       int K) {
    const float* s = sst + b * SS;
    float a0 = 0.f, a1 = 0.f, a2 = 0.f, a3 = 0.f;
#pragma unroll 8
    for (int k = 0; k < K; k += 4) {
        float4 h = *(const float4*)(s + k);
        float4 w = *(const float4*)(W0 + k);
        a0 = fmaf(w.x, h.x, a0);
        a1 = fmaf(w.y, h.y, a1);
        a2 = fmaf(w.z, h.z, a2);
        a3 = fmaf(w.w, h.w, a3);
    }
    return (a0 + a1) + (a2 + a3);
}

__global__ void bar_init(int* bar) {
    for (int i = threadIdx.x; i < 512; i += 256) bar[i] = 0;
}

__global__ __launch_bounds__(NT, 1) void gru_fused(
    const float* __restrict__ x, const float* __restrict__ h0in,
    const float* __restrict__ Wx0, const float* __restrict__ Wh0,
    const float* __restrict__ bh0, const float* __restrict__ Wx1,
    const float* __restrict__ Wh1, const float* __restrict__ bh1,
    const float* __restrict__ Why, const float* __restrict__ bhy,
    float* __restrict__ out, float* __restrict__ ws) {
    __shared__ float sst[32 * SS];  // 33.3 KB
    const int wg = blockIdx.x;
    const int tid = threadIdx.x;
    int* bar = (int*)(ws + 180224);
    int ep = 0;

    // workspace (floats), cross-block data: coherent access only
    float* h0 = ws;             // [b*512+j]
    float* h1 = ws + 16384;
    float* xzr0 = ws + 32768;   // [b*1024+j]
    float* xg0 = ws + 65536;    // [b*512+j] (aliased as xg1 in C/D)
    float* z0 = ws + 81920;
    float* rh0 = ws + 98304;
    float* hzr1 = ws + 114688;  // [b*1024+j]
    float* z1 = ws + 147456;
    float* rh1 = ws + 163840;
    float* xg1 = xg0;

    // ---- pre-loop: init states (WG 0-127); xzr0 for t=0 (WG 128-255) ----
    if (wg < 128) {
        int i = wg * NT + tid;  // 32768 = B*L*H exactly
        int b = i >> 10, l = (i >> 9) & 1, j = i & 511;
        st_coh((l ? h1 : h0) + b * Hq + j, h0in[i]);
    } else {
        stage128p(sst, x, (long)Sq * Iq);  // x_0
        int lid = (wg - 128) * 128 + tid;
        if (tid < 128) {
            int b = lid & 31, jj = lid >> 5;  // jj < 512
            float2 p = dotC2(sst, Wx0 + jj * Iq, Wx0 + (jj + Hq) * Iq, b, Iq);
            st_coh(xzr0 + b * 1024 + jj, p.x);
            st_coh(xzr0 + b * 1024 + jj + Hq, p.y);
        }
    }
    gridbar(bar, ++ep);

    for (int t = 0;; ++t) {
        // ---- phase A (epilogue at t==S) ----
        if (t == Sq) {
            if (wg < 128) {
                int i = wg * NT + tid;  // hidden_state dump
                out[(size_t)Bq * Sq * Oq + i] =
                    ld_coh((((i >> 9) & 1) ? h1 : h0) + (i >> 10) * Hq +
                           (i & 511));
            } else if (wg >= 192) {
                int lid = (wg - 192) * 64 + tid;
                int b = lid & 31, o = lid >> 5;
                float acc = 0.f;
                for (int kb = 0; kb < Hq; kb += KB) {
                    stage256(sst, h1, Hq, kb);
                    if (tid < 64) acc += dotC1(sst, Why + o * Hq + kb, b, KB);
                }
                if (tid < 64)
                    out[((size_t)b * Sq + (Sq - 1)) * Oq + o] = acc + bhy[o];
            }
            break;
        }
        if (wg < 128) {
            // A1: z0, r0, rh0
            int lid = wg * 128 + tid;
            bool act = tid < 128;
            int b = lid & 31, jj = lid >> 5;  // jj < 512
            const float* W0 = Wh0 + jj * Hq;
            const float* W1 = W0 + Hq * Hq;
            float ax = 0.f, ay = 0.f;
            for (int kb = 0; kb < Hq; kb += KB) {
                stage256(sst, h0, Hq, kb);
                if (act) {
                    float2 p = dotC2(sst, W0 + kb, W1 + kb, b, KB);
                    ax += p.x;
                    ay += p.y;
                }
            }
            if (act) {
                float z =
                    sigmoidf_(ld_coh(xzr0 + b * 1024 + jj) + ax + bh0[jj]);
                float r = sigmoidf_(ld_coh(xzr0 + b * 1024 + jj + Hq) + ay +
                                    bh0[jj + Hq]);
                st_coh(z0 + b * Hq + jj, z);
                st_coh(rh0 + b * Hq + jj, r * ld_coh(h0 + b * Hq + jj));
            }
        } else if (wg < 192) {
            // A2: xg0 = x_t @ Wx0_g^T
            stage128p(sst, x + (long)t * Iq, (long)Sq * Iq);
            int lid = (wg - 128) * 128 + tid;
            if (tid < 128) {
                int b = lid & 31, jj = lid >> 5;  // jj < 256
                const float* W0 = Wx0 + (2 * Hq + jj) * Iq;
                float2 p = dotC2(sst, W0, W0 + 256 * Iq, b, Iq);
                st_coh(xg0 + b * Hq + jj, p.x);
                st_coh(xg0 + b * Hq + jj + 256, p.y);
            }
        } else {
            // A3: y_{t-1}
            int lid = (wg - 192) * 64 + tid;
            bool act = tid < 64;
            int b = lid & 31, o = lid >> 5;  // o < 128
            float acc = 0.f;
            for (int kb = 0; kb < Hq; kb += KB) {
                stage256(sst, h1, Hq, kb);
                if (act) acc += dotC1(sst, Why + o * Hq + kb, b, KB);
            }
            if (act && t > 0)
                out[((size_t)b * Sq + (t - 1)) * Oq + o] = acc + bhy[o];
        }
        gridbar(bar, ++ep);

        // ---- phase B ----
        if (wg < 128) {
            // B1: g0, h0 update
            int lid = wg * 64 + tid;
            bool act = tid < 64;
            int b = lid & 31, jj = lid >> 5;  // jj < 256
            const float* W0 = Wh0 + (2 * Hq + jj) * Hq;
            const float* W1 = W0 + 256 * Hq;
            float ax = 0.f, ay = 0.f;
            for (int kb = 0; kb < Hq; kb += KB) {
                stage256(sst, rh0, Hq, kb);
                if (act) {
                    float2 p = dotC2(sst, W0 + kb, W1 + kb, b, KB);
                    ax += p.x;
                    ay += p.y;
                }
            }
            if (act) {
#pragma unroll
                for (int u = 0; u < 2; ++u) {
                    int j = jj + u * 256;
                    float g = tanhf(ld_coh(xg0 + b * Hq + j) + (u ? ay : ax) +
                                    bh0[2 * Hq + j]);
                    float zz = ld_coh(z0 + b * Hq + j);
                    float hold = ld_coh(h0 + b * Hq + j);
                    st_coh(h0 + b * Hq + j, zz * hold + (1.f - zz) * g);
                }
            }
        } else {
            // B2: hzr1 = h1 @ Wh1_zr^T + bh1_zr
            int lid = (wg - 128) * 128 + tid;
            bool act = tid < 128;
            int b = lid & 31, jj = lid >> 5;  // jj < 512
            const float* W0 = Wh1 + jj * Hq;
            const float* W1 = W0 + Hq * Hq;
            float ax = 0.f, ay = 0.f;
            for (int kb = 0; kb < Hq; kb += KB) {
                stage256(sst, h1, Hq, kb);
                if (act) {
                    float2 p = dotC2(sst, W0 + kb, W1 + kb, b, KB);
                    ax += p.x;
                    ay += p.y;
                }
            }
            if (act) {
                st_coh(hzr1 + b * 1024 + jj, ax + bh1[jj]);
                st_coh(hzr1 + b * 1024 + jj + Hq, ay + bh1[jj + Hq]);
            }
        }
        gridbar(bar, ++ep);

        // ---- phase C: consume updated h0 (= s0) ----
        if (wg < 128) {
            // C1: z1, rh1
            int lid = wg * 128 + tid;
            bool act = tid < 128;
            int b = lid & 31, jj = lid >> 5;  // jj < 512
            const float* W0 = Wx1 + jj * Hq;
            const float* W1 = W0 + Hq * Hq;
            float ax = 0.f, ay = 0.f;
            for (int kb = 0; kb < Hq; kb += KB) {
                stage256(sst, h0, Hq, kb);
                if (act) {
                    float2 p = dotC2(sst, W0 + kb, W1 + kb, b, KB);
                    ax += p.x;
                    ay += p.y;
                }
            }
            if (act) {
                float z = sigmoidf_(ax + ld_coh(hzr1 + b * 1024 + jj));
                float r = sigmoidf_(ay + ld_coh(hzr1 + b * 1024 + jj + Hq));
                st_coh(z1 + b * Hq + jj, z);
                st_coh(rh1 + b * Hq + jj, r * ld_coh(h1 + b * Hq + jj));
            }
        } else {
            // C2: xg1 = s0 @ Wx1_g^T
            int lid = (wg - 128) * 64 + tid;
            bool act = tid < 64;
            int b = lid & 31, jj = lid >> 5;  // jj < 256
            const float* W0 = Wx1 + (2 * Hq + jj) * Hq;
            const float* W1 = W0 + 256 * Hq;
            float ax = 0.f, ay = 0.f;
            for (int kb = 0; kb < Hq; kb += KB) {
                stage256(sst, h0, Hq, kb);
                if (act) {
                    float2 p = dotC2(sst, W0 + kb, W1 + kb, b, KB);
                    ax += p.x;
                    ay += p.y;
                }
            }
            if (act) {
                st_coh(xg1 + b * Hq + jj, ax);
                st_coh(xg1 + b * Hq + jj + 256, ay);
            }
        }
        gridbar(bar, ++ep);

        // ---- phase D ----
        if (wg < 128) {
            // D1: g1, h1 update
            int lid = wg * 64 + tid;
            bool act = tid < 64;
            int b = lid & 31, jj = lid >> 5;  // jj < 256
            const float* W0 = Wh1 + (2 * Hq + jj) * Hq;
            const float* W1 = W0 + 256 * Hq;
            float ax = 0.f, ay = 0.f;
            for (int kb = 0; kb < Hq; kb += KB) {
                stage256(sst, rh1, Hq, kb);
                if (act) {
                    float2 p = dotC2(sst, W0 + kb, W1 + kb, b, KB);
                    ax += p.x;
                    ay += p.y;
                }
            }
            if (act) {
#pragma unroll
                for (int u = 0; u < 2; ++u) {
                    int j = jj + u * 256;
                    float g = tanhf(ld_coh(xg1 + b * Hq + j) + (u ? ay : ax) +
                                    bh1[2 * Hq + j]);
                    float zz = ld_coh(z1 + b * Hq + j);
                    float hold = ld_coh(h1 + b * Hq + j);
                    st_coh(h1 + b * Hq + j, zz * hold + (1.f - zz) * g);
                }
            }
        } else if (t + 1 < Sq) {
            // D2: xzr0 for t+1
            stage128p(sst, x + (long)(t + 1) * Iq, (long)Sq * Iq);
            int lid = (wg - 128) * 128 + tid;
            if (tid < 128) {
                int b = lid & 31, jj = lid >> 5;  // jj < 512
                float2 p =
                    dotC2(sst, Wx0 + jj * Iq, Wx0 + (jj + Hq) * Iq, b, Iq);
                st_coh(xzr0 + b * 1024 + jj, p.x);
                st_coh(xzr0 + b * 1024 + jj + Hq, p.y);
            }
        }
        gridbar(bar, ++ep);
    }
}

extern "C" void kernel_launch(void* const* d_in, const int* in_sizes, int n_in,
                              void* d_out, int out_size, void* d_ws,
                              size_t ws_size, hipStream_t stream) {
    const float* x = (const float*)d_in[0];
    const float* h0in = (const float*)d_in[1];
    const float* Wx0 = (const float*)d_in[2];
    const float* Wh0 = (const float*)d_in[3];
    const float* bh0 = (const float*)d_in[4];
    const float* Wx1 = (const float*)d_in[5];
    const float* Wh1 = (const float*)d_in[6];
    const float* bh1 = (const float*)d_in[7];
    const float* Why = (const float*)d_in[8];
    const float* bhy = (const float*)d_in[9];
    float* out = (float*)d_out;
    float* ws = (float*)d_ws;
    int* bar = (int*)(ws + 180224);

    bar_init<<<1, 256, 0, stream>>>(bar);
    gru_fused<<<dim3(NWG), dim3(NT), 0, stream>>>(x, h0in, Wx0, Wh0, bh0, Wx1,
                                                  Wh1, bh1, Why, bhy, out, ws);
}